// Round 9
// baseline (202.134 us; speedup 1.0000x reference)
//
#include <hip/hip_runtime.h>
#include <cstdint>
#include <cstddef>

#define B_  16
#define N_  512
#define D_  256
#define H_  8
#define DK_ 32
// Round 9: 2 dispatches.
//  1) fused_pre: QKV MFMA GEMMs + stats (g_STb bf16) + Wo->bf16 conv.
//  2) attn: S^T orientation (acc = mfma(K,Q) -> D[key][q]):
//     - softmax: per-lane column partials, 2 shuffles, scalar inv
//     - mask: one int4 per 16 keys
//     - P transpose: 2x ds_write_b64 + 1x ds_read_b128 per chunk (dbuf)
//     - ST read from global bf16 (L2-hot via b=bid&15 XCD swizzle)
//     - fused output projection (Phase C) unchanged.
// Packed bf16 cvt via v_cvt_pk_bf16_f32 when available (RNE fallback).

#define QKV_ELEMS 2097152   // B*N*D

__device__ __align__(16) unsigned short g_Qb[QKV_ELEMS];          // [B,H,N,DK] bf16
__device__ __align__(16) unsigned short g_Kb[QKV_ELEMS];          // [B,H,N,DK] bf16
__device__ __align__(16) unsigned short g_VT[QKV_ELEMS];          // [B,H,DK,N] bf16
__device__ __align__(16) unsigned short g_STb[(size_t)B_*N_*N_];  // [B,N,N] bf16
__device__ __align__(16) unsigned short g_WoB[D_*D_];             // Wo bf16 [n][k]

typedef short v8s __attribute__((ext_vector_type(8)));
typedef float v4f __attribute__((ext_vector_type(4)));

__device__ __forceinline__ unsigned short f2b(float f){
  unsigned int x;
  __builtin_memcpy(&x, &f, 4);
  x = x + 0x7FFFu + ((x >> 16) & 1u);   // round-to-nearest-even
  return (unsigned short)(x >> 16);
}

#if defined(__has_builtin)
#if __has_builtin(__builtin_amdgcn_cvt_pk_bf16_f32)
#define PK_BF16 1
#endif
#endif

__device__ __forceinline__ unsigned int pk2(float a, float b){
#ifdef PK_BF16
  typedef __bf16 v2bf __attribute__((ext_vector_type(2)));
  v2bf r = __builtin_amdgcn_cvt_pk_bf16_f32(a, b);
  unsigned int u;
  __builtin_memcpy(&u, &r, 4);
  return u;
#else
  return (unsigned int)f2b(a) | ((unsigned int)f2b(b) << 16);
#endif
}
__device__ __forceinline__ v8s pk8(const float4 a, const float4 b){
  union { unsigned int u[4]; v8s v; } x;
  x.u[0] = pk2(a.x, a.y); x.u[1] = pk2(a.z, a.w);
  x.u[2] = pk2(b.x, b.y); x.u[3] = pk2(b.z, b.w);
  return x.v;
}

// ---------------------------------------------------------------------------
// Dispatch 1: [0,1536) QKV GEMMs; [1536,9728) stats; [9728,9792) Wo conv.
// GEMM: C[m][n] = sum_k A[m][k]*W[n][k] + b[n], M=8192, N=K=256.
// block = 64m x 64n (4 waves x 16 m-rows); W tile fp32->bf16 staged to LDS.
// z==2 (V): operands swapped -> D[n][tok] -> coalesced transposed store.
// stats: ST[row][k] = 0.3*softmax_valid(-dist)[k] + 0.4*adj[k]/(sum adj+eps).
// ---------------------------------------------------------------------------
__global__ __launch_bounds__(256) void fused_pre(
    const float* __restrict__ query, const float* __restrict__ key_,
    const float* __restrict__ value, const float* __restrict__ dist,
    const float* __restrict__ adjm,  const int* __restrict__ mask,
    const float* __restrict__ Wq, const float* __restrict__ bq,
    const float* __restrict__ Wk, const float* __restrict__ bk,
    const float* __restrict__ Wv, const float* __restrict__ bv,
    const float* __restrict__ Wo)
{
  __shared__ unsigned short Wl[64*264];   // 33.8 KB
  __shared__ float red[8];
  __shared__ float coef[2];
  const int bid = blockIdx.x;
  const int t   = threadIdx.x;

  if (bid < 1536){
    const int z  = bid >> 9;                 // 0:Q 1:K 2:V
    const int rr = bid & 511;
    const int mt = rr >> 2, nt = rr & 3;     // nt fastest: A-tile L2 sharing
    const float* Ap = (z==0) ? query : (z==1) ? key_ : value;
    const float* Wp = (z==0) ? Wq : (z==1) ? Wk : Wv;
    const float* bp = (z==0) ? bq : (z==1) ? bk : bv;
    const int w = t >> 6, lane = t & 63, kl = lane & 15, quad = lane >> 4;
    const int m0 = mt*64 + w*16;
    const int n0 = nt*64;

    {   // stage + convert W tile [n0..n0+63][0..255]
      const int row = t >> 2;
      const int ks  = (t & 3) * 64;
      const float* src = Wp + (size_t)(n0+row)*256 + ks;
      unsigned short* dst = Wl + row*264 + ks;
      #pragma unroll
      for (int u = 0; u < 8; ++u){
        const float4 u0 = reinterpret_cast<const float4*>(src)[2*u];
        const float4 u1 = reinterpret_cast<const float4*>(src)[2*u+1];
        *reinterpret_cast<v8s*>(dst + u*8) = pk8(u0, u1);
      }
    }
    __syncthreads();

    v4f acc[4];
    #pragma unroll
    for (int nb = 0; nb < 4; ++nb) acc[nb] = (v4f){0.f,0.f,0.f,0.f};
    const int arow = m0 + kl;

    if (z == 2){
      #pragma unroll
      for (int k0 = 0; k0 < 256; k0 += 32){
        const float* ap = Ap + (size_t)arow*256 + k0 + quad*8;
        const v8s af = pk8(reinterpret_cast<const float4*>(ap)[0],
                           reinterpret_cast<const float4*>(ap)[1]);
        #pragma unroll
        for (int nb = 0; nb < 4; ++nb){
          const v8s wf = *reinterpret_cast<const v8s*>(&Wl[(nb*16+kl)*264 + k0 + quad*8]);
          acc[nb] = __builtin_amdgcn_mfma_f32_16x16x32_bf16(wf, af, acc[nb], 0, 0, 0);
        }
      }
      const int tok = m0 + kl, bb = tok >> 9, nr = tok & 511;
      #pragma unroll
      for (int nb = 0; nb < 4; ++nb)
        #pragma unroll
        for (int r = 0; r < 4; ++r){
          const int n = n0 + nb*16 + quad*4 + r;
          const float v = acc[nb][r] + bp[n];
          g_VT[(((size_t)bb*H_ + (n>>5))*DK_ + (n&31))*N_ + nr] = f2b(v);
        }
    } else {
      #pragma unroll
      for (int k0 = 0; k0 < 256; k0 += 32){
        const float* ap = Ap + (size_t)arow*256 + k0 + quad*8;
        const v8s af = pk8(reinterpret_cast<const float4*>(ap)[0],
                           reinterpret_cast<const float4*>(ap)[1]);
        #pragma unroll
        for (int nb = 0; nb < 4; ++nb){
          const v8s wf = *reinterpret_cast<const v8s*>(&Wl[(nb*16+kl)*264 + k0 + quad*8]);
          acc[nb] = __builtin_amdgcn_mfma_f32_16x16x32_bf16(af, wf, acc[nb], 0, 0, 0);
        }
      }
      unsigned short* dst = z ? g_Kb : g_Qb;
      #pragma unroll
      for (int nb = 0; nb < 4; ++nb){
        const int n = n0 + nb*16 + kl;
        const float bias = bp[n];
        #pragma unroll
        for (int r = 0; r < 4; ++r){
          const int m = m0 + quad*4 + r;
          const float v = acc[nb][r] + bias;
          dst[(((size_t)(m>>9)*H_ + (n>>5))*N_ + (m&511))*DK_ + (n&31)] = f2b(v);
        }
      }
    }
    return;
  }

  if (bid < 9728){
    // ---- stats: one (b,q) row per block, 256 thr x float2 ----
    const int row = bid - 1536;          // b*512 + q
    const int b   = row >> 9;
    const float2 d2 = reinterpret_cast<const float2*>(dist + (size_t)row*N_)[t];
    const float2 a2 = reinterpret_cast<const float2*>(adjm + (size_t)row*N_)[t];
    const int2   m2 = reinterpret_cast<const int2*>(mask + b*N_)[t];
    const float e0 = m2.x ? __expf(-d2.x) : 0.f;   // -dist in [-1,0]: exp-safe
    const float e1 = m2.y ? __expf(-d2.y) : 0.f;
    float lz = e0 + e1;
    float la = a2.x + a2.y;
    #pragma unroll
    for (int o = 1; o < 64; o <<= 1){
      lz += __shfl_xor(lz, o, 64);
      la += __shfl_xor(la, o, 64);
    }
    const int wid = t >> 6;
    if ((t & 63) == 0){ red[wid] = lz; red[4+wid] = la; }
    __syncthreads();
    if (t == 0){
      const float Z = red[0] + red[1] + red[2] + red[3];
      const float S = red[4] + red[5] + red[6] + red[7];
      coef[0] = (Z > 0.f) ? 0.3f / Z : 0.f;
      coef[1] = 0.4f / (S + 1e-6f);
    }
    __syncthreads();
    const float c0 = coef[0], c1 = coef[1];
    reinterpret_cast<unsigned int*>(g_STb + (size_t)row*N_)[t] =
        pk2(e0*c0 + a2.x*c1, e1*c0 + a2.y*c1);
    return;
  }

  // ---- Wo fp32 -> bf16 (64 blocks x 256 thr x 4) ----
  const int i = ((bid - 9728)*256 + t)*4;
  const float4 u = *reinterpret_cast<const float4*>(Wo + i);
  uint2 o2;
  o2.x = pk2(u.x, u.y);
  o2.y = pk2(u.z, u.w);
  *reinterpret_cast<uint2*>(g_WoB + i) = o2;
}

// ---------------------------------------------------------------------------
// Dispatch 2: attention megablock. 512 thr = 8 waves = 8 heads; one (b,qtile).
// S^T = K Q^T: acc[kb] = mfma(A=K-frag, B=Q-frag) -> D[key=quad*4+r][q=kl].
// Column softmax: per-lane partial + shfl_xor(16,32); single inv scalar.
// P transpose to LDS: 2x b64 writes + 1x b128 read per 32-key chunk (dbuf).
// PV: O^T += mfma(V^T rows, P-frag) + mfma(V^T rows, ST-frag from global).
// Phase C: out = X @ Wo^T + bo with X in LDS (bf16), Wo bf16 from L2.
// ---------------------------------------------------------------------------
__global__ __launch_bounds__(512) void attn_kernel(
    const int* __restrict__ mask, const float* __restrict__ bo,
    float* __restrict__ out)
{
  __shared__ unsigned short Pl[8*2*640];    // 20.5 KB: per-wave double-buffered 16x40
  __shared__ unsigned short Xl[16*264];     //  8.4 KB: X[qrow][n] bf16
  const int bid = blockIdx.x;
  const int b  = bid & 15;                  // same-b -> same XCD (L2 K/V/ST reuse)
  const int qt = bid >> 4;
  const int q0 = qt*16;
  const int t  = threadIdx.x;
  const int w  = t >> 6, lane = t & 63;
  const int kl = lane & 15, quad = lane >> 4;
  const int h  = w;
  const size_t bh = (size_t)b*H_ + h;
  const float scale = 0.17677669529663687f;   // 1/sqrt(32)

  const unsigned short* Qp = g_Qb + (bh*N_ + q0)*DK_;
  const unsigned short* Kp = g_Kb + bh*N_*DK_;
  const unsigned short* Vp = g_VT + bh*DK_*N_;
  const unsigned short* Sp = g_STb + ((size_t)(b*N_ + q0))*N_;
  const int* mrow = mask + b*N_;
  const v4f vz = {0.f, 0.f, 0.f, 0.f};

  // Q B-frag: B[d=quad*8+j][q=kl] = Q[q0+kl][quad*8+j]
  const v8s aq = *reinterpret_cast<const v8s*>(Qp + (size_t)kl*DK_ + quad*8);

  // ---- S^T = K Q^T ----
  v4f acc[32];
  #pragma unroll
  for (int kb = 0; kb < 32; ++kb){
    const v8s ak = *reinterpret_cast<const v8s*>(Kp + (size_t)(kb*16 + kl)*DK_ + quad*8);
    acc[kb] = __builtin_amdgcn_mfma_f32_16x16x32_bf16(ak, aq, vz, 0, 0, 0);
  }

  // ---- mask + exp + column sum (no max-sub: |s*scale| small, exp-safe) ----
  float psum = 0.f;
  #pragma unroll
  for (int kb = 0; kb < 32; ++kb){
    const int4 mv = reinterpret_cast<const int4*>(mrow + kb*16)[quad];
    acc[kb][0] = mv.x ? __expf(acc[kb][0]*scale) : 0.f;
    acc[kb][1] = mv.y ? __expf(acc[kb][1]*scale) : 0.f;
    acc[kb][2] = mv.z ? __expf(acc[kb][2]*scale) : 0.f;
    acc[kb][3] = mv.w ? __expf(acc[kb][3]*scale) : 0.f;
    psum += (acc[kb][0] + acc[kb][1]) + (acc[kb][2] + acc[kb][3]);
  }
  psum += __shfl_xor(psum, 16, 64);
  psum += __shfl_xor(psum, 32, 64);
  const float inv = (psum > 0.f) ? 0.3f / psum : 0.f;

  // ---- PV over 16 chunks of 32 keys ----
  unsigned short* Pw = Pl + w*1280;
  v4f o0 = vz, o1 = vz;
  #pragma unroll
  for (int c = 0; c < 16; ++c){
    unsigned short* Pb = Pw + (c & 1)*640;
    {
      union { unsigned int u[2]; unsigned long long ll; } p0, p1;
      p0.u[0] = pk2(acc[2*c  ][0]*inv, acc[2*c  ][1]*inv);
      p0.u[1] = pk2(acc[2*c  ][2]*inv, acc[2*c  ][3]*inv);
      p1.u[0] = pk2(acc[2*c+1][0]*inv, acc[2*c+1][1]*inv);
      p1.u[1] = pk2(acc[2*c+1][2]*inv, acc[2*c+1][3]*inv);
      // lane holds P[q=kl][key = c*32 + {quad*4..+3, 16+quad*4..+3}]
      *reinterpret_cast<unsigned long long*>(&Pb[kl*40 + quad*4])      = p0.ll;
      *reinterpret_cast<unsigned long long*>(&Pb[kl*40 + 16 + quad*4]) = p1.ll;
    }
    // B-frag: P[q=kl][key = c*32 + quad*8 + j]  (same-wave, lgkm-ordered)
    const v8s bp  = *reinterpret_cast<const v8s*>(&Pb[kl*40 + quad*8]);
    const v8s bst = *reinterpret_cast<const v8s*>(Sp + (size_t)kl*N_ + c*32 + quad*8);
    const v8s av0 = *reinterpret_cast<const v8s*>(Vp + (size_t)(     kl)*N_ + c*32 + quad*8);
    const v8s av1 = *reinterpret_cast<const v8s*>(Vp + (size_t)(16 + kl)*N_ + c*32 + quad*8);
    o0 = __builtin_amdgcn_mfma_f32_16x16x32_bf16(av0, bp,  o0, 0, 0, 0);
    o0 = __builtin_amdgcn_mfma_f32_16x16x32_bf16(av0, bst, o0, 0, 0, 0);
    o1 = __builtin_amdgcn_mfma_f32_16x16x32_bf16(av1, bp,  o1, 0, 0, 0);
    o1 = __builtin_amdgcn_mfma_f32_16x16x32_bf16(av1, bst, o1, 0, 0, 0);
  }

  // ---- X[q=kl][h*32 + d'] bf16 into LDS (lane holds O^T[d'=quad*4+r][q=kl]) ----
  {
    unsigned short* xr = Xl + kl*264 + h*32;
    *reinterpret_cast<unsigned int*>(&xr[quad*4])        = pk2(o0[0], o0[1]);
    *reinterpret_cast<unsigned int*>(&xr[quad*4 + 2])    = pk2(o0[2], o0[3]);
    *reinterpret_cast<unsigned int*>(&xr[16 + quad*4])     = pk2(o1[0], o1[1]);
    *reinterpret_cast<unsigned int*>(&xr[16 + quad*4 + 2]) = pk2(o1[2], o1[3]);
  }
  __syncthreads();

  // ---- Phase C: out = X @ Wo^T + bo; wave w -> n in [w*32, w*32+32) ----
  {
    const int n0 = w*32;
    v4f a20 = vz, a21 = vz;
    #pragma unroll
    for (int k0 = 0; k0 < 256; k0 += 32){
      const v8s af  = *reinterpret_cast<const v8s*>(&Xl[kl*264 + k0 + quad*8]);
      const v8s wf0 = *reinterpret_cast<const v8s*>(g_WoB + (size_t)(n0 + kl)*256 + k0 + quad*8);
      const v8s wf1 = *reinterpret_cast<const v8s*>(g_WoB + (size_t)(n0 + 16 + kl)*256 + k0 + quad*8);
      a20 = __builtin_amdgcn_mfma_f32_16x16x32_bf16(af, wf0, a20, 0, 0, 0);
      a21 = __builtin_amdgcn_mfma_f32_16x16x32_bf16(af, wf1, a21, 0, 0, 0);
    }
    const int n_0 = n0 + kl, n_1 = n0 + 16 + kl;
    const float b0v = bo[n_0], b1v = bo[n_1];
    #pragma unroll
    for (int r = 0; r < 4; ++r){
      const size_t m = (size_t)(b*N_ + q0 + quad*4 + r);
      out[m*256 + n_0] = a20[r] + b0v;
      out[m*256 + n_1] = a21[r] + b1v;
    }
  }
}

extern "C" void kernel_launch(void* const* d_in, const int* in_sizes, int n_in,
                              void* d_out, int out_size, void* d_ws, size_t ws_size,
                              hipStream_t stream)
{
  const float* query = (const float*)d_in[0];
  const float* key_  = (const float*)d_in[1];
  const float* value = (const float*)d_in[2];
  const float* adjm  = (const float*)d_in[3];
  const float* dist  = (const float*)d_in[4];
  // d_in[5] = edges_att (unused)
  const int*   mask  = (const int*)d_in[6];
  const float* Wq = (const float*)d_in[7];  const float* bq = (const float*)d_in[8];
  const float* Wk = (const float*)d_in[9];  const float* bk = (const float*)d_in[10];
  const float* Wv = (const float*)d_in[11]; const float* bv = (const float*)d_in[12];
  const float* Wo = (const float*)d_in[13]; const float* bo = (const float*)d_in[14];

  fused_pre<<<9792, 256, 0, stream>>>(query, key_, value, dist, adjm, mask,
                                      Wq, bq, Wk, bk, Wv, bv, Wo);
  attn_kernel<<<512, 512, 0, stream>>>(mask, bo, (float*)d_out);
}

// Round 10
// 198.072 us; speedup vs baseline: 1.0205x; 1.0205x over previous
//
#include <hip/hip_runtime.h>
#include <cstdint>
#include <cstddef>

#define B_  16
#define N_  512
#define D_  256
#define H_  8
#define DK_ 32
// Round 10: 3 dispatches, zero-LDS pre-stage.
//  1) conv_w: Wq/Wk/Wv/Wo fp32->bf16 into g_Wb (L2-hot for later reads).
//  2) fused_mid: QKV MFMA GEMMs with W-frags read DIRECTLY from g_Wb via
//     global v8s (no LDS, no barrier — r9's 34KB-LDS-in-every-block killed
//     occupancy at 29%); stats one-row-per-WAVE (wave reduce only, no LDS).
//  3) attn: r9 S^T structure (column softmax, b64 P-transpose, fused Wo proj).

#define QKV_ELEMS 2097152   // B*N*D

__device__ __align__(16) unsigned short g_Qb[QKV_ELEMS];          // [B,H,N,DK] bf16
__device__ __align__(16) unsigned short g_Kb[QKV_ELEMS];          // [B,H,N,DK] bf16
__device__ __align__(16) unsigned short g_VT[QKV_ELEMS];          // [B,H,DK,N] bf16
__device__ __align__(16) unsigned short g_STb[(size_t)B_*N_*N_];  // [B,N,N] bf16
__device__ __align__(16) unsigned short g_Wb[4*D_*D_];            // Wq,Wk,Wv,Wo bf16

typedef short v8s __attribute__((ext_vector_type(8)));
typedef float v4f __attribute__((ext_vector_type(4)));

__device__ __forceinline__ unsigned short f2b(float f){
  unsigned int x;
  __builtin_memcpy(&x, &f, 4);
  x = x + 0x7FFFu + ((x >> 16) & 1u);   // round-to-nearest-even
  return (unsigned short)(x >> 16);
}

#if defined(__has_builtin)
#if __has_builtin(__builtin_amdgcn_cvt_pk_bf16_f32)
#define PK_BF16 1
#endif
#endif

__device__ __forceinline__ unsigned int pk2(float a, float b){
#ifdef PK_BF16
  typedef __bf16 v2bf __attribute__((ext_vector_type(2)));
  v2bf r = __builtin_amdgcn_cvt_pk_bf16_f32(a, b);
  unsigned int u;
  __builtin_memcpy(&u, &r, 4);
  return u;
#else
  return (unsigned int)f2b(a) | ((unsigned int)f2b(b) << 16);
#endif
}
__device__ __forceinline__ v8s pk8(const float4 a, const float4 b){
  union { unsigned int u[4]; v8s v; } x;
  x.u[0] = pk2(a.x, a.y); x.u[1] = pk2(a.z, a.w);
  x.u[2] = pk2(b.x, b.y); x.u[3] = pk2(b.z, b.w);
  return x.v;
}

// ---------------------------------------------------------------------------
// Dispatch 1: weights fp32 -> bf16. 256 blocks (64 per matrix) x 256 thr x 4.
// ---------------------------------------------------------------------------
__global__ __launch_bounds__(256) void conv_w(
    const float* __restrict__ Wq, const float* __restrict__ Wk,
    const float* __restrict__ Wv, const float* __restrict__ Wo)
{
  const int widx = blockIdx.x >> 6;
  const int i = ((blockIdx.x & 63)*256 + threadIdx.x)*4;
  const float* src = (widx==0) ? Wq : (widx==1) ? Wk : (widx==2) ? Wv : Wo;
  const float4 u = *reinterpret_cast<const float4*>(src + i);
  uint2 o2;
  o2.x = pk2(u.x, u.y);
  o2.y = pk2(u.z, u.w);
  *reinterpret_cast<uint2*>(g_Wb + widx*65536 + i) = o2;
}

// ---------------------------------------------------------------------------
// Dispatch 2: blocks [0,1536): QKV MFMA GEMMs (no LDS, W-frags from g_Wb);
//             blocks [1536,3584): stats, one (b,q) row per wave.
// GEMM: C[m][n] = sum_k A[m][k]*W[n][k] + b[n], M=8192, N=K=256.
// wave = 16m x 64n; A-frag = 2 x float4 + pack; W-frag = global v8s (L2-hot).
// z==2 (V): operands swapped -> D[n][tok] -> coalesced transposed store.
// stats: ST[row][k] = 0.3*softmax_valid(-dist)[k] + 0.4*adj[k]/(sum adj+eps);
// exp without max-sub (-dist in [-1,0] is exp-safe).
// ---------------------------------------------------------------------------
__global__ __launch_bounds__(256) void fused_mid(
    const float* __restrict__ query, const float* __restrict__ key_,
    const float* __restrict__ value, const float* __restrict__ dist,
    const float* __restrict__ adjm,  const int* __restrict__ mask,
    const float* __restrict__ bq, const float* __restrict__ bk,
    const float* __restrict__ bv)
{
  const int bid = blockIdx.x;
  const int t   = threadIdx.x;
  const int w = t >> 6, lane = t & 63, kl = lane & 15, quad = lane >> 4;

  if (bid < 1536){
    const int z  = bid >> 9;                 // 0:Q 1:K 2:V
    const int rr = bid & 511;
    const int mt = rr >> 2, nt = rr & 3;     // nt fastest: A-tile L2 sharing
    const float* Ap = (z==0) ? query : (z==1) ? key_ : value;
    const float* bp = (z==0) ? bq : (z==1) ? bk : bv;
    const unsigned short* Wb = g_Wb + z*65536;
    const int m0 = mt*64 + w*16;
    const int n0 = nt*64;

    v4f acc[4];
    #pragma unroll
    for (int nb = 0; nb < 4; ++nb) acc[nb] = (v4f){0.f,0.f,0.f,0.f};
    const int arow = m0 + kl;

    if (z == 2){
      #pragma unroll
      for (int k0 = 0; k0 < 256; k0 += 32){
        const float* ap = Ap + (size_t)arow*256 + k0 + quad*8;
        const v8s af = pk8(reinterpret_cast<const float4*>(ap)[0],
                           reinterpret_cast<const float4*>(ap)[1]);
        #pragma unroll
        for (int nb = 0; nb < 4; ++nb){
          const v8s wf = *reinterpret_cast<const v8s*>(
              Wb + (size_t)(n0 + nb*16 + kl)*256 + k0 + quad*8);
          acc[nb] = __builtin_amdgcn_mfma_f32_16x16x32_bf16(wf, af, acc[nb], 0, 0, 0);
        }
      }
      const int tok = m0 + kl, bb = tok >> 9, nr = tok & 511;
      #pragma unroll
      for (int nb = 0; nb < 4; ++nb)
        #pragma unroll
        for (int r = 0; r < 4; ++r){
          const int n = n0 + nb*16 + quad*4 + r;
          const float v = acc[nb][r] + bp[n];
          g_VT[(((size_t)bb*H_ + (n>>5))*DK_ + (n&31))*N_ + nr] = f2b(v);
        }
    } else {
      #pragma unroll
      for (int k0 = 0; k0 < 256; k0 += 32){
        const float* ap = Ap + (size_t)arow*256 + k0 + quad*8;
        const v8s af = pk8(reinterpret_cast<const float4*>(ap)[0],
                           reinterpret_cast<const float4*>(ap)[1]);
        #pragma unroll
        for (int nb = 0; nb < 4; ++nb){
          const v8s wf = *reinterpret_cast<const v8s*>(
              Wb + (size_t)(n0 + nb*16 + kl)*256 + k0 + quad*8);
          acc[nb] = __builtin_amdgcn_mfma_f32_16x16x32_bf16(af, wf, acc[nb], 0, 0, 0);
        }
      }
      unsigned short* dst = z ? g_Kb : g_Qb;
      #pragma unroll
      for (int nb = 0; nb < 4; ++nb){
        const int n = n0 + nb*16 + kl;
        const float bias = bp[n];
        #pragma unroll
        for (int r = 0; r < 4; ++r){
          const int m = m0 + quad*4 + r;
          const float v = acc[nb][r] + bias;
          dst[(((size_t)(m>>9)*H_ + (n>>5))*N_ + (m&511))*DK_ + (n&31)] = f2b(v);
        }
      }
    }
    return;
  }

  // ---- stats: row = (bid-1536)*4 + w; 64 lanes x 8 elems; wave reduce ----
  {
    const int row = (bid - 1536)*4 + w;      // b*512 + q
    const int b   = row >> 9;
    const size_t roff = (size_t)row*N_ + lane*8;
    const float4 d0 = *reinterpret_cast<const float4*>(dist + roff);
    const float4 d1 = *reinterpret_cast<const float4*>(dist + roff + 4);
    const float4 a0 = *reinterpret_cast<const float4*>(adjm + roff);
    const float4 a1 = *reinterpret_cast<const float4*>(adjm + roff + 4);
    const int4   m0v = *reinterpret_cast<const int4*>(mask + b*N_ + lane*8);
    const int4   m1v = *reinterpret_cast<const int4*>(mask + b*N_ + lane*8 + 4);
    float e[8], a[8];
    e[0] = m0v.x ? __expf(-d0.x) : 0.f;  e[1] = m0v.y ? __expf(-d0.y) : 0.f;
    e[2] = m0v.z ? __expf(-d0.z) : 0.f;  e[3] = m0v.w ? __expf(-d0.w) : 0.f;
    e[4] = m1v.x ? __expf(-d1.x) : 0.f;  e[5] = m1v.y ? __expf(-d1.y) : 0.f;
    e[6] = m1v.z ? __expf(-d1.z) : 0.f;  e[7] = m1v.w ? __expf(-d1.w) : 0.f;
    a[0]=a0.x; a[1]=a0.y; a[2]=a0.z; a[3]=a0.w;
    a[4]=a1.x; a[5]=a1.y; a[6]=a1.z; a[7]=a1.w;
    float lz = 0.f, la = 0.f;
    #pragma unroll
    for (int i = 0; i < 8; ++i){ lz += e[i]; la += a[i]; }
    #pragma unroll
    for (int o = 1; o < 64; o <<= 1){
      lz += __shfl_xor(lz, o, 64);
      la += __shfl_xor(la, o, 64);
    }
    const float c0 = (lz > 0.f) ? 0.3f / lz : 0.f;
    const float c1 = 0.4f / (la + 1e-6f);
    uint4 o4;
    o4.x = pk2(e[0]*c0 + a[0]*c1, e[1]*c0 + a[1]*c1);
    o4.y = pk2(e[2]*c0 + a[2]*c1, e[3]*c0 + a[3]*c1);
    o4.z = pk2(e[4]*c0 + a[4]*c1, e[5]*c0 + a[5]*c1);
    o4.w = pk2(e[6]*c0 + a[6]*c1, e[7]*c0 + a[7]*c1);
    *reinterpret_cast<uint4*>(g_STb + roff) = o4;
  }
}

// ---------------------------------------------------------------------------
// Dispatch 3: attention megablock. 512 thr = 8 waves = 8 heads; one (b,qtile).
// S^T = K Q^T -> D[key][q]; column softmax (2 shuffles, scalar inv);
// P transpose: 2x ds_write_b64 + 1x ds_read_b128 per 32-key chunk (dbuf);
// PV: O^T += mfma(V^T, P) + mfma(V^T, ST from g_STb); fused Wo projection.
// ---------------------------------------------------------------------------
__global__ __launch_bounds__(512) void attn_kernel(
    const int* __restrict__ mask, const float* __restrict__ bo,
    float* __restrict__ out)
{
  __shared__ unsigned short Pl[8*2*640];    // 20.5 KB: per-wave dbuf 16x40
  __shared__ unsigned short Xl[16*264];     //  8.4 KB: X[qrow][n] bf16
  const int bid = blockIdx.x;
  const int b  = bid & 15;                  // same-b -> same XCD (L2 K/V/ST reuse)
  const int qt = bid >> 4;
  const int q0 = qt*16;
  const int t  = threadIdx.x;
  const int w  = t >> 6, lane = t & 63;
  const int kl = lane & 15, quad = lane >> 4;
  const int h  = w;
  const size_t bh = (size_t)b*H_ + h;
  const float scale = 0.17677669529663687f;   // 1/sqrt(32)

  const unsigned short* Qp = g_Qb + (bh*N_ + q0)*DK_;
  const unsigned short* Kp = g_Kb + bh*N_*DK_;
  const unsigned short* Vp = g_VT + bh*DK_*N_;
  const unsigned short* Sp = g_STb + ((size_t)(b*N_ + q0))*N_;
  const int* mrow = mask + b*N_;
  const v4f vz = {0.f, 0.f, 0.f, 0.f};

  // Q B-frag: B[d=quad*8+j][q=kl] = Q[q0+kl][quad*8+j]
  const v8s aq = *reinterpret_cast<const v8s*>(Qp + (size_t)kl*DK_ + quad*8);

  // ---- S^T = K Q^T ----
  v4f acc[32];
  #pragma unroll
  for (int kb = 0; kb < 32; ++kb){
    const v8s ak = *reinterpret_cast<const v8s*>(Kp + (size_t)(kb*16 + kl)*DK_ + quad*8);
    acc[kb] = __builtin_amdgcn_mfma_f32_16x16x32_bf16(ak, aq, vz, 0, 0, 0);
  }

  // ---- mask + exp + column sum (no max-sub: |s*scale| small, exp-safe) ----
  float psum = 0.f;
  #pragma unroll
  for (int kb = 0; kb < 32; ++kb){
    const int4 mv = reinterpret_cast<const int4*>(mrow + kb*16)[quad];
    acc[kb][0] = mv.x ? __expf(acc[kb][0]*scale) : 0.f;
    acc[kb][1] = mv.y ? __expf(acc[kb][1]*scale) : 0.f;
    acc[kb][2] = mv.z ? __expf(acc[kb][2]*scale) : 0.f;
    acc[kb][3] = mv.w ? __expf(acc[kb][3]*scale) : 0.f;
    psum += (acc[kb][0] + acc[kb][1]) + (acc[kb][2] + acc[kb][3]);
  }
  psum += __shfl_xor(psum, 16, 64);
  psum += __shfl_xor(psum, 32, 64);
  const float inv = (psum > 0.f) ? 0.3f / psum : 0.f;

  // ---- PV over 16 chunks of 32 keys ----
  unsigned short* Pw = Pl + w*1280;
  v4f o0 = vz, o1 = vz;
  #pragma unroll
  for (int c = 0; c < 16; ++c){
    unsigned short* Pb = Pw + (c & 1)*640;
    {
      union { unsigned int u[2]; unsigned long long ll; } p0, p1;
      p0.u[0] = pk2(acc[2*c  ][0]*inv, acc[2*c  ][1]*inv);
      p0.u[1] = pk2(acc[2*c  ][2]*inv, acc[2*c  ][3]*inv);
      p1.u[0] = pk2(acc[2*c+1][0]*inv, acc[2*c+1][1]*inv);
      p1.u[1] = pk2(acc[2*c+1][2]*inv, acc[2*c+1][3]*inv);
      // lane holds P[q=kl][key = c*32 + {quad*4..+3, 16+quad*4..+3}]
      *reinterpret_cast<unsigned long long*>(&Pb[kl*40 + quad*4])      = p0.ll;
      *reinterpret_cast<unsigned long long*>(&Pb[kl*40 + 16 + quad*4]) = p1.ll;
    }
    // B-frag: P[q=kl][key = c*32 + quad*8 + j]  (same-wave, lgkm-ordered)
    const v8s bp  = *reinterpret_cast<const v8s*>(&Pb[kl*40 + quad*8]);
    const v8s bst = *reinterpret_cast<const v8s*>(Sp + (size_t)kl*N_ + c*32 + quad*8);
    const v8s av0 = *reinterpret_cast<const v8s*>(Vp + (size_t)(     kl)*N_ + c*32 + quad*8);
    const v8s av1 = *reinterpret_cast<const v8s*>(Vp + (size_t)(16 + kl)*N_ + c*32 + quad*8);
    o0 = __builtin_amdgcn_mfma_f32_16x16x32_bf16(av0, bp,  o0, 0, 0, 0);
    o0 = __builtin_amdgcn_mfma_f32_16x16x32_bf16(av0, bst, o0, 0, 0, 0);
    o1 = __builtin_amdgcn_mfma_f32_16x16x32_bf16(av1, bp,  o1, 0, 0, 0);
    o1 = __builtin_amdgcn_mfma_f32_16x16x32_bf16(av1, bst, o1, 0, 0, 0);
  }

  // ---- X[q=kl][h*32 + d'] bf16 into LDS (lane holds O^T[d'=quad*4+r][q=kl]) ----
  {
    unsigned short* xr = Xl + kl*264 + h*32;
    *reinterpret_cast<unsigned int*>(&xr[quad*4])          = pk2(o0[0], o0[1]);
    *reinterpret_cast<unsigned int*>(&xr[quad*4 + 2])      = pk2(o0[2], o0[3]);
    *reinterpret_cast<unsigned int*>(&xr[16 + quad*4])     = pk2(o1[0], o1[1]);
    *reinterpret_cast<unsigned int*>(&xr[16 + quad*4 + 2]) = pk2(o1[2], o1[3]);
  }
  __syncthreads();

  // ---- Phase C: out = X @ Wo^T + bo; wave w -> n in [w*32, w*32+32) ----
  {
    const unsigned short* WoB = g_Wb + 3*65536;
    const int n0 = w*32;
    v4f a20 = vz, a21 = vz;
    #pragma unroll
    for (int k0 = 0; k0 < 256; k0 += 32){
      const v8s af  = *reinterpret_cast<const v8s*>(&Xl[kl*264 + k0 + quad*8]);
      const v8s wf0 = *reinterpret_cast<const v8s*>(WoB + (size_t)(n0 + kl)*256 + k0 + quad*8);
      const v8s wf1 = *reinterpret_cast<const v8s*>(WoB + (size_t)(n0 + 16 + kl)*256 + k0 + quad*8);
      a20 = __builtin_amdgcn_mfma_f32_16x16x32_bf16(af, wf0, a20, 0, 0, 0);
      a21 = __builtin_amdgcn_mfma_f32_16x16x32_bf16(af, wf1, a21, 0, 0, 0);
    }
    const int n_0 = n0 + kl, n_1 = n0 + 16 + kl;
    const float b0v = bo[n_0], b1v = bo[n_1];
    #pragma unroll
    for (int r = 0; r < 4; ++r){
      const size_t m = (size_t)(b*N_ + q0 + quad*4 + r);
      out[m*256 + n_0] = a20[r] + b0v;
      out[m*256 + n_1] = a21[r] + b1v;
    }
  }
}

extern "C" void kernel_launch(void* const* d_in, const int* in_sizes, int n_in,
                              void* d_out, int out_size, void* d_ws, size_t ws_size,
                              hipStream_t stream)
{
  const float* query = (const float*)d_in[0];
  const float* key_  = (const float*)d_in[1];
  const float* value = (const float*)d_in[2];
  const float* adjm  = (const float*)d_in[3];
  const float* dist  = (const float*)d_in[4];
  // d_in[5] = edges_att (unused)
  const int*   mask  = (const int*)d_in[6];
  const float* Wq = (const float*)d_in[7];  const float* bq = (const float*)d_in[8];
  const float* Wk = (const float*)d_in[9];  const float* bk = (const float*)d_in[10];
  const float* Wv = (const float*)d_in[11]; const float* bv = (const float*)d_in[12];
  const float* Wo = (const float*)d_in[13]; const float* bo = (const float*)d_in[14];

  conv_w<<<256, 256, 0, stream>>>(Wq, Wk, Wv, Wo);
  fused_mid<<<3584, 256, 0, stream>>>(query, key_, value, dist, adjm, mask,
                                      bq, bk, bv);
  attn_kernel<<<512, 512, 0, stream>>>(mask, bo, (float*)d_out);
}